// Round 1
// baseline (945.182 us; speedup 1.0000x reference)
//
#include <hip/hip_runtime.h>

typedef _Float16 f16;
typedef _Float16 f16x8 __attribute__((ext_vector_type(8)));
typedef float f32x4 __attribute__((ext_vector_type(4)));

#define MFMA16(a, b, c) __builtin_amdgcn_mfma_f32_16x16x32_f16(a, b, c, 0, 0, 0)

// ---------------- Kernel 1: per-(tensor,b,c) mean / inv-std ----------------
__global__ __launch_bounds__(256) void stats_kernel(
    const float* __restrict__ content, const float* __restrict__ style,
    float* __restrict__ mu, float* __restrict__ rs)
{
    int bid = blockIdx.x;            // tensor*2048 + b*512 + c
    int tensor = bid >> 11;
    int row = bid & 2047;
    const float* src = (tensor ? style : content) + (size_t)row * 4096;
    int t = threadIdx.x;
    float s = 0.f, ss = 0.f;
    for (int i = t; i < 1024; i += 256) {
        float4 v = reinterpret_cast<const float4*>(src)[i];
        s  += v.x + v.y + v.z + v.w;
        ss += v.x * v.x + v.y * v.y + v.z * v.z + v.w * v.w;
    }
    for (int off = 32; off > 0; off >>= 1) {
        s  += __shfl_down(s, off);
        ss += __shfl_down(ss, off);
    }
    __shared__ float sb[4], ssb[4];
    int wv = t >> 6;
    if ((t & 63) == 0) { sb[wv] = s; ssb[wv] = ss; }
    __syncthreads();
    if (t == 0) {
        float S  = sb[0] + sb[1] + sb[2] + sb[3];
        float SS = ssb[0] + ssb[1] + ssb[2] + ssb[3];
        float m  = S * (1.f / 4096.f);
        float var = (SS - 4096.f * m * m) * (1.f / 4095.f);
        mu[bid] = m;
        rs[bid] = rsqrtf(var + 1e-5f);
    }
}

// ---------------- Kernel 2: fused norm + 1x1-conv (Q,K,V) -----------------
// p=0: Q = Wq @ norm(content)+bq  -> Qt[b][n][o]   (pixel-major)
// p=1: K = Wk @ norm(style)+bk    -> Kt[b][n][o]   (pixel-major)
// p=2: V = Wv @ style+bv          -> Vc[b][o][n]   (channel-major)
__global__ __launch_bounds__(256) void qkv_kernel(
    const float* __restrict__ content, const float* __restrict__ style,
    const float* __restrict__ Wq, const float* __restrict__ bq,
    const float* __restrict__ Wk, const float* __restrict__ bk,
    const float* __restrict__ Wv, const float* __restrict__ bv,
    const float* __restrict__ mu, const float* __restrict__ rs,
    f16* __restrict__ Qt, f16* __restrict__ Kt, f16* __restrict__ Vc)
{
    int z = blockIdx.z;
    int b = z / 3, p = z % 3;
    int n0 = blockIdx.x * 128;
    int o0 = blockIdx.y * 128;
    const float* X    = (p == 0 ? content : style) + (size_t)b * 512 * 4096;
    const float* W    = (p == 0 ? Wq : (p == 1 ? Wk : Wv));
    const float* bias = (p == 0 ? bq : (p == 1 ? bk : bv));
    const float* muT = mu + (p == 0 ? 0 : 2048) + b * 512;
    const float* rsT = rs + (p == 0 ? 0 : 2048) + b * 512;
    bool norm = (p < 2);

    __shared__ __align__(16) f16 Xt[128][40];  // X^T tile: [n][c], padded
    __shared__ __align__(16) f16 Wl[128][40];  // W tile:   [o][c], padded

    int t = threadIdx.x;
    int lane = t & 63, w = t >> 6;
    int wn = (w & 1) * 64, wo = (w >> 1) * 64;
    int lg = lane >> 4, li = lane & 15;

    f32x4 acc[4][4];
#pragma unroll
    for (int i = 0; i < 4; ++i)
#pragma unroll
        for (int j = 0; j < 4; ++j)
#pragma unroll
            for (int e = 0; e < 4; ++e) acc[i][j][e] = 0.f;

    for (int kk = 0; kk < 16; ++kk) {
        int c0 = kk * 32;
        __syncthreads();
        // stage X transposed (+ fused normalization)
#pragma unroll
        for (int r = 0; r < 4; ++r) {
            int linear = r * 256 + t;
            int c  = linear >> 5;       // 0..31
            int nq = linear & 31;       // float4 index
            float4 v = reinterpret_cast<const float4*>(X + (size_t)(c0 + c) * 4096 + n0)[nq];
            float m = 0.f, sc = 1.f;
            if (norm) { m = muT[c0 + c]; sc = rsT[c0 + c]; }
            int n = nq * 4;
            Xt[n + 0][c] = (f16)((v.x - m) * sc);
            Xt[n + 1][c] = (f16)((v.y - m) * sc);
            Xt[n + 2][c] = (f16)((v.z - m) * sc);
            Xt[n + 3][c] = (f16)((v.w - m) * sc);
        }
        // stage W
#pragma unroll
        for (int r = 0; r < 4; ++r) {
            int linear = r * 256 + t;
            int o  = linear >> 3;       // 0..127
            int cq = linear & 7;
            float4 v = reinterpret_cast<const float4*>(W + (size_t)(o0 + o) * 512 + c0)[cq];
            int c = cq * 4;
            Wl[o][c + 0] = (f16)v.x;
            Wl[o][c + 1] = (f16)v.y;
            Wl[o][c + 2] = (f16)v.z;
            Wl[o][c + 3] = (f16)v.w;
        }
        __syncthreads();

        f16x8 xf[4], wf[4];
#pragma unroll
        for (int f = 0; f < 4; ++f) {
            xf[f] = *reinterpret_cast<const f16x8*>(&Xt[wn + f * 16 + li][lg * 8]);
            wf[f] = *reinterpret_cast<const f16x8*>(&Wl[wo + f * 16 + li][lg * 8]);
        }
        if (p < 2) {            // D[n][o] = X^T * W^T(as B)
#pragma unroll
            for (int i = 0; i < 4; ++i)
#pragma unroll
                for (int j = 0; j < 4; ++j)
                    acc[i][j] = MFMA16(xf[i], wf[j], acc[i][j]);
        } else {                // D[o][n] = W * X
#pragma unroll
            for (int i = 0; i < 4; ++i)
#pragma unroll
                for (int j = 0; j < 4; ++j)
                    acc[i][j] = MFMA16(wf[i], xf[j], acc[i][j]);
        }
    }

    if (p < 2) {
        f16* dst = (p == 0 ? Qt : Kt) + (size_t)b * 4096 * 512;
#pragma unroll
        for (int j = 0; j < 4; ++j) {
            int o = o0 + wo + j * 16 + li;
            float bb = bias[o];
#pragma unroll
            for (int i = 0; i < 4; ++i)
#pragma unroll
                for (int e = 0; e < 4; ++e) {
                    int n = n0 + wn + i * 16 + lg * 4 + e;
                    dst[(size_t)n * 512 + o] = (f16)(acc[i][j][e] + bb);
                }
        }
    } else {
#pragma unroll
        for (int i = 0; i < 4; ++i)
#pragma unroll
            for (int e = 0; e < 4; ++e) {
                int o = o0 + wo + i * 16 + lg * 4 + e;
                float bb = bias[o];
#pragma unroll
                for (int j = 0; j < 4; ++j) {
                    int n = n0 + wn + j * 16 + li;
                    Vc[((size_t)b * 512 + o) * 4096 + n] = (f16)(acc[i][j][e] + bb);
                }
            }
    }
}

// ---------------- Kernel 3: flash attention --------------------------------
// block: 64 q-rows (n0..n0+64), 4 waves; wave w owns q-rows w*16..+16 for S,
// and c-slice w*128..+128 for PV output. TK=32 kv pixels per iteration.
__global__ __launch_bounds__(256, 2) void attn_kernel(
    const f16* __restrict__ Qt, const f16* __restrict__ Kt,
    const f16* __restrict__ Vc, float* __restrict__ out)
{
    int b = blockIdx.y;
    int n0 = blockIdx.x * 64;
    int t = threadIdx.x;
    int lane = t & 63, w = t >> 6;
    int lg = lane >> 4, li = lane & 15;

    __shared__ __align__(16) f16 Km[32][520];   // K tile [m][c]
    __shared__ __align__(16) f16 Vl[512][40];   // V tile [c][m]
    __shared__ __align__(16) f16 Pl[64][40];    // P tile [n][m]
    __shared__ float Mrow[64], Lrow[64], Rrow[64];

    const f16* Qb = Qt + (size_t)b * 4096 * 512;
    const f16* Kb = Kt + (size_t)b * 4096 * 512;
    const f16* Vb = Vc + (size_t)b * 512 * 4096;

    // Q fragments for this wave's 16 rows, pinned in registers
    f16x8 qf[16];
#pragma unroll
    for (int kk = 0; kk < 16; ++kk)
        qf[kk] = *reinterpret_cast<const f16x8*>(
            Qb + (size_t)(n0 + w * 16 + li) * 512 + kk * 32 + lg * 8);

    if (t < 64) { Mrow[t] = -__builtin_inff(); Lrow[t] = 0.f; }

    f32x4 oacc[4][8];   // [n-frag][c-frag]
#pragma unroll
    for (int i = 0; i < 4; ++i)
#pragma unroll
        for (int j = 0; j < 8; ++j)
#pragma unroll
            for (int e = 0; e < 4; ++e) oacc[i][j][e] = 0.f;

    for (int m0 = 0; m0 < 4096; m0 += 32) {
        __syncthreads();
        // stage K tile [32][512]
#pragma unroll
        for (int r = 0; r < 8; ++r) {
            int linear = r * 256 + t;
            int mm = linear >> 6;
            int c  = (linear & 63) * 8;
            *reinterpret_cast<f16x8*>(&Km[mm][c]) =
                *reinterpret_cast<const f16x8*>(Kb + (size_t)(m0 + mm) * 512 + c);
        }
        // stage V tile [512][32]
#pragma unroll
        for (int r = 0; r < 8; ++r) {
            int linear = r * 256 + t;
            int c = linear >> 2;
            int m = (linear & 3) * 8;
            *reinterpret_cast<f16x8*>(&Vl[c][m]) =
                *reinterpret_cast<const f16x8*>(Vb + (size_t)c * 4096 + m0 + m);
        }
        __syncthreads();

        // S = Q^T K : this wave's 16 rows x 32 cols
        f32x4 s0, s1;
#pragma unroll
        for (int e = 0; e < 4; ++e) { s0[e] = 0.f; s1[e] = 0.f; }
#pragma unroll
        for (int kk = 0; kk < 16; ++kk) {
            f16x8 b0 = *reinterpret_cast<const f16x8*>(&Km[li][kk * 32 + lg * 8]);
            f16x8 b1 = *reinterpret_cast<const f16x8*>(&Km[16 + li][kk * 32 + lg * 8]);
            s0 = MFMA16(qf[kk], b0, s0);
            s1 = MFMA16(qf[kk], b1, s1);
        }

        // wave-parallel online softmax (rows n = w*16 + lg*4 + e, cols = li / 16+li)
        float rmx[4], p0[4], p1[4], rsum[4], rr[4], Mnew[4];
#pragma unroll
        for (int e = 0; e < 4; ++e) rmx[e] = fmaxf(s0[e], s1[e]);
#pragma unroll
        for (int off = 1; off < 16; off <<= 1)
#pragma unroll
            for (int e = 0; e < 4; ++e) rmx[e] = fmaxf(rmx[e], __shfl_xor(rmx[e], off));
#pragma unroll
        for (int e = 0; e < 4; ++e) {
            int row = w * 16 + lg * 4 + e;
            float Mold = Mrow[row];
            Mnew[e] = fmaxf(Mold, rmx[e]);
            rr[e] = __expf(Mold - Mnew[e]);
            p0[e] = __expf(s0[e] - Mnew[e]);
            p1[e] = __expf(s1[e] - Mnew[e]);
            rsum[e] = p0[e] + p1[e];
        }
#pragma unroll
        for (int off = 1; off < 16; off <<= 1)
#pragma unroll
            for (int e = 0; e < 4; ++e) rsum[e] += __shfl_xor(rsum[e], off);
        if (li == 0) {
#pragma unroll
            for (int e = 0; e < 4; ++e) {
                int row = w * 16 + lg * 4 + e;
                Mrow[row] = Mnew[e];
                Lrow[row] = Lrow[row] * rr[e] + rsum[e];
                Rrow[row] = rr[e];
            }
        }
#pragma unroll
        for (int e = 0; e < 4; ++e) {
            int row = w * 16 + lg * 4 + e;
            Pl[row][li]      = (f16)p0[e];
            Pl[row][16 + li] = (f16)p1[e];
        }
        __syncthreads();

        // rescale O, then O += P * V   (D[n][c], K-dim = m = 32)
#pragma unroll
        for (int fn = 0; fn < 4; ++fn) {
            float rv[4];
#pragma unroll
            for (int e = 0; e < 4; ++e) rv[e] = Rrow[fn * 16 + lg * 4 + e];
#pragma unroll
            for (int fc = 0; fc < 8; ++fc)
#pragma unroll
                for (int e = 0; e < 4; ++e) oacc[fn][fc][e] *= rv[e];
        }
        f16x8 af[4];
#pragma unroll
        for (int fn = 0; fn < 4; ++fn)
            af[fn] = *reinterpret_cast<const f16x8*>(&Pl[fn * 16 + li][lg * 8]);
#pragma unroll
        for (int fc = 0; fc < 8; ++fc) {
            f16x8 vfr = *reinterpret_cast<const f16x8*>(&Vl[w * 128 + fc * 16 + li][lg * 8]);
#pragma unroll
            for (int fn = 0; fn < 4; ++fn)
                oacc[fn][fc] = MFMA16(af[fn], vfr, oacc[fn][fc]);
        }
    }

    // epilogue: divide by L, store out[b][c][n]
    float* ob = out + (size_t)b * 512 * 4096;
#pragma unroll
    for (int fn = 0; fn < 4; ++fn) {
        float linv[4];
#pragma unroll
        for (int e = 0; e < 4; ++e) linv[e] = 1.f / Lrow[fn * 16 + lg * 4 + e];
#pragma unroll
        for (int fc = 0; fc < 8; ++fc) {
            int c = w * 128 + fc * 16 + li;
#pragma unroll
            for (int e = 0; e < 4; ++e) {
                int n = n0 + fn * 16 + lg * 4 + e;
                ob[(size_t)c * 4096 + n] = oacc[fn][fc][e] * linv[e];
            }
        }
    }
}

// ---------------------------------------------------------------------------
extern "C" void kernel_launch(void* const* d_in, const int* in_sizes, int n_in,
                              void* d_out, int out_size, void* d_ws, size_t ws_size,
                              hipStream_t stream)
{
    const float* content = (const float*)d_in[0];
    const float* style   = (const float*)d_in[1];
    const float* Wq = (const float*)d_in[2];
    const float* bq = (const float*)d_in[3];
    const float* Wk = (const float*)d_in[4];
    const float* bk = (const float*)d_in[5];
    const float* Wv = (const float*)d_in[6];
    const float* bv = (const float*)d_in[7];
    float* out = (float*)d_out;

    const size_t TEN = (size_t)4 * 4096 * 512;   // elements per Q/K/V tensor
    f16* Qt = (f16*)d_ws;
    f16* Kt = Qt + TEN;
    f16* Vc = Kt + TEN;
    float* mu = (float*)(Vc + TEN);
    float* rs = mu + 4096;

    hipLaunchKernelGGL(stats_kernel, dim3(4096), dim3(256), 0, stream,
                       content, style, mu, rs);
    hipLaunchKernelGGL(qkv_kernel, dim3(32, 4, 12), dim3(256), 0, stream,
                       content, style, Wq, bq, Wk, bk, Wv, bv, mu, rs, Qt, Kt, Vc);
    hipLaunchKernelGGL(attn_kernel, dim3(64, 4), dim3(256), 0, stream,
                       Qt, Kt, Vc, out);
}

// Round 2
// 619.867 us; speedup vs baseline: 1.5248x; 1.5248x over previous
//
#include <hip/hip_runtime.h>

typedef _Float16 f16;
typedef _Float16 f16x8 __attribute__((ext_vector_type(8)));
typedef float f32x4 __attribute__((ext_vector_type(4)));

#define MFMA16(a, b, c) __builtin_amdgcn_mfma_f32_16x16x32_f16(a, b, c, 0, 0, 0)

// ---------------- Kernel 1: per-(tensor,b,c) mean / inv-std ----------------
__global__ __launch_bounds__(256) void stats_kernel(
    const float* __restrict__ content, const float* __restrict__ style,
    float* __restrict__ mu, float* __restrict__ rs)
{
    int bid = blockIdx.x;            // tensor*2048 + b*512 + c
    int tensor = bid >> 11;
    int row = bid & 2047;
    const float* src = (tensor ? style : content) + (size_t)row * 4096;
    int t = threadIdx.x;
    float s = 0.f, ss = 0.f;
    for (int i = t; i < 1024; i += 256) {
        float4 v = reinterpret_cast<const float4*>(src)[i];
        s  += v.x + v.y + v.z + v.w;
        ss += v.x * v.x + v.y * v.y + v.z * v.z + v.w * v.w;
    }
    for (int off = 32; off > 0; off >>= 1) {
        s  += __shfl_down(s, off);
        ss += __shfl_down(ss, off);
    }
    __shared__ float sb[4], ssb[4];
    int wv = t >> 6;
    if ((t & 63) == 0) { sb[wv] = s; ssb[wv] = ss; }
    __syncthreads();
    if (t == 0) {
        float S  = sb[0] + sb[1] + sb[2] + sb[3];
        float SS = ssb[0] + ssb[1] + ssb[2] + ssb[3];
        float m  = S * (1.f / 4096.f);
        float var = (SS - 4096.f * m * m) * (1.f / 4095.f);
        mu[bid] = m;
        rs[bid] = rsqrtf(var + 1e-5f);
    }
}

// ---------------- Kernel 2: fused norm + 1x1-conv (Q,K,V) -----------------
__global__ __launch_bounds__(256) void qkv_kernel(
    const float* __restrict__ content, const float* __restrict__ style,
    const float* __restrict__ Wq, const float* __restrict__ bq,
    const float* __restrict__ Wk, const float* __restrict__ bk,
    const float* __restrict__ Wv, const float* __restrict__ bv,
    const float* __restrict__ mu, const float* __restrict__ rs,
    f16* __restrict__ Qt, f16* __restrict__ Kt, f16* __restrict__ Vc)
{
    int z = blockIdx.z;
    int b = z / 3, p = z % 3;
    int n0 = blockIdx.x * 128;
    int o0 = blockIdx.y * 128;
    const float* X    = (p == 0 ? content : style) + (size_t)b * 512 * 4096;
    const float* W    = (p == 0 ? Wq : (p == 1 ? Wk : Wv));
    const float* bias = (p == 0 ? bq : (p == 1 ? bk : bv));
    const float* muT = mu + (p == 0 ? 0 : 2048) + b * 512;
    const float* rsT = rs + (p == 0 ? 0 : 2048) + b * 512;
    bool norm = (p < 2);

    __shared__ __align__(16) f16 Xt[128][40];
    __shared__ __align__(16) f16 Wl[128][40];

    int t = threadIdx.x;
    int lane = t & 63, w = t >> 6;
    int wn = (w & 1) * 64, wo = (w >> 1) * 64;
    int lg = lane >> 4, li = lane & 15;

    f32x4 acc[4][4];
#pragma unroll
    for (int i = 0; i < 4; ++i)
#pragma unroll
        for (int j = 0; j < 4; ++j)
#pragma unroll
            for (int e = 0; e < 4; ++e) acc[i][j][e] = 0.f;

    for (int kk = 0; kk < 16; ++kk) {
        int c0 = kk * 32;
        __syncthreads();
#pragma unroll
        for (int r = 0; r < 4; ++r) {
            int linear = r * 256 + t;
            int c  = linear >> 5;
            int nq = linear & 31;
            float4 v = reinterpret_cast<const float4*>(X + (size_t)(c0 + c) * 4096 + n0)[nq];
            float m = 0.f, sc = 1.f;
            if (norm) { m = muT[c0 + c]; sc = rsT[c0 + c]; }
            int n = nq * 4;
            Xt[n + 0][c] = (f16)((v.x - m) * sc);
            Xt[n + 1][c] = (f16)((v.y - m) * sc);
            Xt[n + 2][c] = (f16)((v.z - m) * sc);
            Xt[n + 3][c] = (f16)((v.w - m) * sc);
        }
#pragma unroll
        for (int r = 0; r < 4; ++r) {
            int linear = r * 256 + t;
            int o  = linear >> 3;
            int cq = linear & 7;
            float4 v = reinterpret_cast<const float4*>(W + (size_t)(o0 + o) * 512 + c0)[cq];
            int c = cq * 4;
            Wl[o][c + 0] = (f16)v.x;
            Wl[o][c + 1] = (f16)v.y;
            Wl[o][c + 2] = (f16)v.z;
            Wl[o][c + 3] = (f16)v.w;
        }
        __syncthreads();

        f16x8 xf[4], wf[4];
#pragma unroll
        for (int f = 0; f < 4; ++f) {
            xf[f] = *reinterpret_cast<const f16x8*>(&Xt[wn + f * 16 + li][lg * 8]);
            wf[f] = *reinterpret_cast<const f16x8*>(&Wl[wo + f * 16 + li][lg * 8]);
        }
        if (p < 2) {
#pragma unroll
            for (int i = 0; i < 4; ++i)
#pragma unroll
                for (int j = 0; j < 4; ++j)
                    acc[i][j] = MFMA16(xf[i], wf[j], acc[i][j]);
        } else {
#pragma unroll
            for (int i = 0; i < 4; ++i)
#pragma unroll
                for (int j = 0; j < 4; ++j)
                    acc[i][j] = MFMA16(wf[i], xf[j], acc[i][j]);
        }
    }

    if (p < 2) {
        f16* dst = (p == 0 ? Qt : Kt) + (size_t)b * 4096 * 512;
#pragma unroll
        for (int j = 0; j < 4; ++j) {
            int o = o0 + wo + j * 16 + li;
            float bb = bias[o];
#pragma unroll
            for (int i = 0; i < 4; ++i)
#pragma unroll
                for (int e = 0; e < 4; ++e) {
                    int n = n0 + wn + i * 16 + lg * 4 + e;
                    dst[(size_t)n * 512 + o] = (f16)(acc[i][j][e] + bb);
                }
        }
    } else {
#pragma unroll
        for (int i = 0; i < 4; ++i)
#pragma unroll
            for (int e = 0; e < 4; ++e) {
                int o = o0 + wo + i * 16 + lg * 4 + e;
                float bb = bias[o];
#pragma unroll
                for (int j = 0; j < 4; ++j) {
                    int n = n0 + wn + j * 16 + li;
                    Vc[((size_t)b * 512 + o) * 4096 + n] = (f16)(acc[i][j][e] + bb);
                }
            }
    }
}

// ---------------- Kernel 3: flash attention, 8-wave ------------------------
// block: 512 threads (8 waves), TQ=64 q-rows, KVBLK=32. grid (64,4).
// QK:  wave w computes S-tile (n-frag = w&3, m-frag = w>>2), 16 MFMA.
// softmax: wave w owns rows w*8..w*8+8, wave-parallel (32-lane reduce).
// PV:  wave w owns c-slice w*64..+64, all 64 n-rows, 16 MFMA.
__global__ __launch_bounds__(512, 2) void attn_kernel(
    const f16* __restrict__ Qt, const f16* __restrict__ Kt,
    const f16* __restrict__ Vc, float* __restrict__ out)
{
    int b = blockIdx.y;
    int n0 = blockIdx.x * 64;
    int t = threadIdx.x;
    int lane = t & 63, w = t >> 6;
    int lg = lane >> 4, li = lane & 15;

    __shared__ __align__(16) f16 Km[2][32][520];   // K dbuf [m][c]
    __shared__ __align__(16) f16 Vl[512][40];      // V tile [c][m]
    __shared__ __align__(16) float Sl[64][33];     // scores f32 [n][m]
    __shared__ __align__(16) f16 Pl[64][38];       // probs  f16 [n][m]
    __shared__ float Mrow[64], Lrow[64], Rrow[64];
    __shared__ int Rflag[2];

    const f16* Qb = Qt + (size_t)b * 4096 * 512;
    const f16* Kb = Kt + (size_t)b * 4096 * 512;
    const f16* Vb = Vc + (size_t)b * 512 * 4096;

    int aq = w & 3;          // QK n-frag
    int mh = w >> 2;         // QK m-frag

    // Q fragments pinned in registers: rows n0 + aq*16 + li, k = 0..511
    f16x8 qf[16];
#pragma unroll
    for (int kk = 0; kk < 16; ++kk)
        qf[kk] = *reinterpret_cast<const f16x8*>(
            Qb + (size_t)(n0 + aq * 16 + li) * 512 + kk * 32 + lg * 8);

    if (t < 64) { Mrow[t] = -3.4e38f; Lrow[t] = 0.f; Rrow[t] = 1.f; }
    if (t == 0) { Rflag[0] = 0; Rflag[1] = 0; }

    f32x4 acc[4][4];
#pragma unroll
    for (int i = 0; i < 4; ++i)
#pragma unroll
        for (int j = 0; j < 4; ++j)
#pragma unroll
            for (int e = 0; e < 4; ++e) acc[i][j][e] = 0.f;

    // prologue: stage K tile 0 into Km[0] (4 rows per wave, 1 KB each)
#pragma unroll
    for (int i = 0; i < 4; ++i) {
        int r = w * 4 + i;
        *reinterpret_cast<f16x8*>(&Km[0][r][lane * 8]) =
            *reinterpret_cast<const f16x8*>(Kb + (size_t)r * 512 + lane * 8);
    }
    int cur = 0;

    for (int tile = 0; tile < 128; ++tile) {
        int m0 = tile * 32;
        __syncthreads();   // bar_TOP: Vl/Pl free, Km[cur] staged

        // stage V tile [512][32] (4 KB per wave)
#pragma unroll
        for (int i = 0; i < 4; ++i) {
            int c = w * 64 + i * 16 + (lane >> 2);
            int m8 = (lane & 3) * 8;
            *reinterpret_cast<f16x8*>(&Vl[c][m8]) =
                *reinterpret_cast<const f16x8*>(Vb + (size_t)c * 4096 + m0 + m8);
        }
        // prefetch next K tile into the other buffer
        if (tile < 127) {
#pragma unroll
            for (int i = 0; i < 4; ++i) {
                int r = w * 4 + i;
                *reinterpret_cast<f16x8*>(&Km[cur ^ 1][r][lane * 8]) =
                    *reinterpret_cast<const f16x8*>(
                        Kb + (size_t)(m0 + 32 + r) * 512 + lane * 8);
            }
        }

        // QK: wave's 16x16 S-tile, two independent 8-deep MFMA chains
        f32x4 sA = {0.f, 0.f, 0.f, 0.f}, sB = {0.f, 0.f, 0.f, 0.f};
        int mr = mh * 16 + li;
#pragma unroll
        for (int kk = 0; kk < 16; kk += 2) {
            f16x8 b0 = *reinterpret_cast<const f16x8*>(&Km[cur][mr][kk * 32 + lg * 8]);
            f16x8 b1 = *reinterpret_cast<const f16x8*>(&Km[cur][mr][(kk + 1) * 32 + lg * 8]);
            sA = MFMA16(qf[kk], b0, sA);
            sB = MFMA16(qf[kk + 1], b1, sB);
        }
        int sr = aq * 16 + lg * 4;
        int sc = mh * 16 + li;
#pragma unroll
        for (int e = 0; e < 4; ++e) Sl[sr + e][sc] = sA[e] + sB[e];
        __syncthreads();   // bar_B: S complete

        // softmax: wave w handles rows w*8 .. w*8+8 (2 rows per pass)
        {
            int m = lane & 31;
            int half = lane >> 5;
#pragma unroll
            for (int p = 0; p < 4; ++p) {
                int r = w * 8 + p * 2 + half;
                float x = Sl[r][m];
                float mx = x;
#pragma unroll
                for (int off = 1; off < 32; off <<= 1)
                    mx = fmaxf(mx, __shfl_xor(mx, off));
                float Mold = Mrow[r];
                bool needR = (mx - Mold) > 4.0f;        // defer-max THR=4
                float Mnew = needR ? mx : Mold;
                float pr = __expf(x - Mnew);
                float rsum = pr;
#pragma unroll
                for (int off = 1; off < 32; off <<= 1)
                    rsum += __shfl_xor(rsum, off);
                Pl[r][m] = (f16)pr;
                if (m == 0) {
                    float rr = needR ? __expf(Mold - Mnew) : 1.f;
                    Mrow[r] = Mnew;
                    Lrow[r] = Lrow[r] * rr + rsum;
                    Rrow[r] = rr;
                    if (needR) Rflag[tile & 1] = 1;
                }
            }
            if (t == 0) Rflag[(tile + 1) & 1] = 0;
        }
        __syncthreads();   // bar_C: P/R ready

        // PV: O[n][c-slice], rescale only when some row updated its max
        if (Rflag[tile & 1]) {
#pragma unroll
            for (int fn = 0; fn < 4; ++fn) {
                float rv[4];
#pragma unroll
                for (int e = 0; e < 4; ++e) rv[e] = Rrow[fn * 16 + lg * 4 + e];
#pragma unroll
                for (int fc = 0; fc < 4; ++fc)
#pragma unroll
                    for (int e = 0; e < 4; ++e) acc[fn][fc][e] *= rv[e];
            }
        }
        f16x8 af[4], vf[4];
#pragma unroll
        for (int fn = 0; fn < 4; ++fn)
            af[fn] = *reinterpret_cast<const f16x8*>(&Pl[fn * 16 + li][lg * 8]);
#pragma unroll
        for (int fc = 0; fc < 4; ++fc)
            vf[fc] = *reinterpret_cast<const f16x8*>(&Vl[w * 64 + fc * 16 + li][lg * 8]);
#pragma unroll
        for (int fn = 0; fn < 4; ++fn)
#pragma unroll
            for (int fc = 0; fc < 4; ++fc)
                acc[fn][fc] = MFMA16(af[fn], vf[fc], acc[fn][fc]);

        cur ^= 1;
    }

    // epilogue: divide by L, store out[b][c][n]
    float* ob = out + (size_t)b * 512 * 4096;
#pragma unroll
    for (int fn = 0; fn < 4; ++fn) {
        float linv[4];
#pragma unroll
        for (int e = 0; e < 4; ++e) linv[e] = 1.f / Lrow[fn * 16 + lg * 4 + e];
#pragma unroll
        for (int fc = 0; fc < 4; ++fc) {
            int c = w * 64 + fc * 16 + li;
#pragma unroll
            for (int e = 0; e < 4; ++e) {
                int n = n0 + fn * 16 + lg * 4 + e;
                ob[(size_t)c * 4096 + n] = acc[fn][fc][e] * linv[e];
            }
        }
    }
}

// ---------------------------------------------------------------------------
extern "C" void kernel_launch(void* const* d_in, const int* in_sizes, int n_in,
                              void* d_out, int out_size, void* d_ws, size_t ws_size,
                              hipStream_t stream)
{
    const float* content = (const float*)d_in[0];
    const float* style   = (const float*)d_in[1];
    const float* Wq = (const float*)d_in[2];
    const float* bq = (const float*)d_in[3];
    const float* Wk = (const float*)d_in[4];
    const float* bk = (const float*)d_in[5];
    const float* Wv = (const float*)d_in[6];
    const float* bv = (const float*)d_in[7];
    float* out = (float*)d_out;

    const size_t TEN = (size_t)4 * 4096 * 512;
    f16* Qt = (f16*)d_ws;
    f16* Kt = Qt + TEN;
    f16* Vc = Kt + TEN;
    float* mu = (float*)(Vc + TEN);
    float* rs = mu + 4096;

    hipLaunchKernelGGL(stats_kernel, dim3(4096), dim3(256), 0, stream,
                       content, style, mu, rs);
    hipLaunchKernelGGL(qkv_kernel, dim3(32, 4, 12), dim3(256), 0, stream,
                       content, style, Wq, bq, Wk, bk, Wv, bv, mu, rs, Qt, Kt, Vc);
    hipLaunchKernelGGL(attn_kernel, dim3(64, 4), dim3(512), 0, stream,
                       Qt, Kt, Vc, out);
}

// Round 3
// 524.176 us; speedup vs baseline: 1.8032x; 1.1826x over previous
//
#include <hip/hip_runtime.h>

typedef _Float16 f16;
typedef _Float16 f16x8 __attribute__((ext_vector_type(8)));
typedef float f32x4 __attribute__((ext_vector_type(4)));

#define MFMA16(a, b, c) __builtin_amdgcn_mfma_f32_16x16x32_f16(a, b, c, 0, 0, 0)

// ---------------- Kernel 1: per-(tensor,b,c) mean / inv-std ----------------
__global__ __launch_bounds__(256) void stats_kernel(
    const float* __restrict__ content, const float* __restrict__ style,
    float* __restrict__ mu, float* __restrict__ rs)
{
    int bid = blockIdx.x;            // tensor*2048 + b*512 + c
    int tensor = bid >> 11;
    int row = bid & 2047;
    const float* src = (tensor ? style : content) + (size_t)row * 4096;
    int t = threadIdx.x;
    float s = 0.f, ss = 0.f;
    for (int i = t; i < 1024; i += 256) {
        float4 v = reinterpret_cast<const float4*>(src)[i];
        s  += v.x + v.y + v.z + v.w;
        ss += v.x * v.x + v.y * v.y + v.z * v.z + v.w * v.w;
    }
    for (int off = 32; off > 0; off >>= 1) {
        s  += __shfl_down(s, off);
        ss += __shfl_down(ss, off);
    }
    __shared__ float sb[4], ssb[4];
    int wv = t >> 6;
    if ((t & 63) == 0) { sb[wv] = s; ssb[wv] = ss; }
    __syncthreads();
    if (t == 0) {
        float S  = sb[0] + sb[1] + sb[2] + sb[3];
        float SS = ssb[0] + ssb[1] + ssb[2] + ssb[3];
        float m  = S * (1.f / 4096.f);
        float var = (SS - 4096.f * m * m) * (1.f / 4095.f);
        mu[bid] = m;
        rs[bid] = rsqrtf(var + 1e-5f);
    }
}

// ---------------- Kernel 2: fused norm + 1x1-conv (Q,K,V) -----------------
__global__ __launch_bounds__(256) void qkv_kernel(
    const float* __restrict__ content, const float* __restrict__ style,
    const float* __restrict__ Wq, const float* __restrict__ bq,
    const float* __restrict__ Wk, const float* __restrict__ bk,
    const float* __restrict__ Wv, const float* __restrict__ bv,
    const float* __restrict__ mu, const float* __restrict__ rs,
    f16* __restrict__ Qt, f16* __restrict__ Kt, f16* __restrict__ Vc)
{
    int z = blockIdx.z;
    int b = z / 3, p = z % 3;
    int n0 = blockIdx.x * 128;
    int o0 = blockIdx.y * 128;
    const float* X    = (p == 0 ? content : style) + (size_t)b * 512 * 4096;
    const float* W    = (p == 0 ? Wq : (p == 1 ? Wk : Wv));
    const float* bias = (p == 0 ? bq : (p == 1 ? bk : bv));
    const float* muT = mu + (p == 0 ? 0 : 2048) + b * 512;
    const float* rsT = rs + (p == 0 ? 0 : 2048) + b * 512;
    bool norm = (p < 2);

    __shared__ __align__(16) f16 Xt[128][40];
    __shared__ __align__(16) f16 Wl[128][40];

    int t = threadIdx.x;
    int lane = t & 63, w = t >> 6;
    int wn = (w & 1) * 64, wo = (w >> 1) * 64;
    int lg = lane >> 4, li = lane & 15;

    f32x4 acc[4][4];
#pragma unroll
    for (int i = 0; i < 4; ++i)
#pragma unroll
        for (int j = 0; j < 4; ++j)
#pragma unroll
            for (int e = 0; e < 4; ++e) acc[i][j][e] = 0.f;

    for (int kk = 0; kk < 16; ++kk) {
        int c0 = kk * 32;
        __syncthreads();
#pragma unroll
        for (int r = 0; r < 4; ++r) {
            int linear = r * 256 + t;
            int c  = linear >> 5;
            int nq = linear & 31;
            float4 v = reinterpret_cast<const float4*>(X + (size_t)(c0 + c) * 4096 + n0)[nq];
            float m = 0.f, sc = 1.f;
            if (norm) { m = muT[c0 + c]; sc = rsT[c0 + c]; }
            int n = nq * 4;
            Xt[n + 0][c] = (f16)((v.x - m) * sc);
            Xt[n + 1][c] = (f16)((v.y - m) * sc);
            Xt[n + 2][c] = (f16)((v.z - m) * sc);
            Xt[n + 3][c] = (f16)((v.w - m) * sc);
        }
#pragma unroll
        for (int r = 0; r < 4; ++r) {
            int linear = r * 256 + t;
            int o  = linear >> 3;
            int cq = linear & 7;
            float4 v = reinterpret_cast<const float4*>(W + (size_t)(o0 + o) * 512 + c0)[cq];
            int c = cq * 4;
            Wl[o][c + 0] = (f16)v.x;
            Wl[o][c + 1] = (f16)v.y;
            Wl[o][c + 2] = (f16)v.z;
            Wl[o][c + 3] = (f16)v.w;
        }
        __syncthreads();

        f16x8 xf[4], wf[4];
#pragma unroll
        for (int f = 0; f < 4; ++f) {
            xf[f] = *reinterpret_cast<const f16x8*>(&Xt[wn + f * 16 + li][lg * 8]);
            wf[f] = *reinterpret_cast<const f16x8*>(&Wl[wo + f * 16 + li][lg * 8]);
        }
        if (p < 2) {
#pragma unroll
            for (int i = 0; i < 4; ++i)
#pragma unroll
                for (int j = 0; j < 4; ++j)
                    acc[i][j] = MFMA16(xf[i], wf[j], acc[i][j]);
        } else {
#pragma unroll
            for (int i = 0; i < 4; ++i)
#pragma unroll
                for (int j = 0; j < 4; ++j)
                    acc[i][j] = MFMA16(wf[i], xf[j], acc[i][j]);
        }
    }

    if (p < 2) {
        f16* dst = (p == 0 ? Qt : Kt) + (size_t)b * 4096 * 512;
#pragma unroll
        for (int j = 0; j < 4; ++j) {
            int o = o0 + wo + j * 16 + li;
            float bb = bias[o];
#pragma unroll
            for (int i = 0; i < 4; ++i)
#pragma unroll
                for (int e = 0; e < 4; ++e) {
                    int n = n0 + wn + i * 16 + lg * 4 + e;
                    dst[(size_t)n * 512 + o] = (f16)(acc[i][j][e] + bb);
                }
        }
    } else {
#pragma unroll
        for (int i = 0; i < 4; ++i)
#pragma unroll
            for (int e = 0; e < 4; ++e) {
                int o = o0 + wo + i * 16 + lg * 4 + e;
                float bb = bias[o];
#pragma unroll
                for (int j = 0; j < 4; ++j) {
                    int n = n0 + wn + j * 16 + li;
                    Vc[((size_t)b * 512 + o) * 4096 + n] = (f16)(acc[i][j][e] + bb);
                }
            }
    }
}

// ---------------- Kernel 3: flash attention, 8-wave, 2-barrier pipeline ----
// 512 thr / 8 waves, TQ=64 q-rows, KVBLK=32, grid (64,4).
// QK: wave w -> S-tile (n-frag = w&3, m-frag = w>>2). softmax: rows w*8..+8.
// PV: wave w -> c-slice w*64..+64 (V frags pulled DIRECTLY from global/L2).
// Pipeline: V(t+1) and K(t+1) loads issued a full tile before use.
__global__ __launch_bounds__(512, 2) void attn_kernel(
    const f16* __restrict__ Qt, const f16* __restrict__ Kt,
    const f16* __restrict__ Vc, float* __restrict__ out)
{
    int b = blockIdx.y;
    int n0 = blockIdx.x * 64;
    int t = threadIdx.x;
    int lane = t & 63, w = t >> 6;
    int lg = lane >> 4, li = lane & 15;

    __shared__ __align__(16) f16 Km[2][32][520];   // K dbuf [m][c], pad 520
    __shared__ __align__(16) float Sl[64][33];     // scores f32 [n][m]
    __shared__ __align__(16) f16 Pl[64][40];       // probs f16 [n][m], 80B rows (16-aligned)
    __shared__ __align__(16) float Mrow[64];
    __shared__ __align__(16) float Lrow[64];
    __shared__ __align__(16) float Rrow[64];
    __shared__ int Rflag[2];

    const f16* Qb = Qt + (size_t)b * 4096 * 512;
    const f16* Kb = Kt + (size_t)b * 4096 * 512;
    const f16* Vb = Vc + (size_t)b * 512 * 4096;

    int aq = w & 3;          // QK n-frag
    int mh = w >> 2;         // QK m-frag

    // Q fragments pinned in registers
    f16x8 qf[16];
#pragma unroll
    for (int kk = 0; kk < 16; ++kk)
        qf[kk] = *reinterpret_cast<const f16x8*>(
            Qb + (size_t)(n0 + aq * 16 + li) * 512 + kk * 32 + lg * 8);

    if (t < 64) { Mrow[t] = -3.4e38f; Lrow[t] = 0.f; Rrow[t] = 1.f; }
    if (t == 0) { Rflag[0] = 0; Rflag[1] = 0; }

    f32x4 acc[4][4];
#pragma unroll
    for (int i = 0; i < 4; ++i)
#pragma unroll
        for (int j = 0; j < 4; ++j)
#pragma unroll
            for (int e = 0; e < 4; ++e) acc[i][j][e] = 0.f;

    // staging registers
    f16x8 kreg[4];           // 4 K rows (wave w owns rows w*4..w*4+4)
    f16x8 vfr[4], vnx[4];    // V frags for tile t / t+1

    const f16* Vbase = Vb + (size_t)(w * 64 + li) * 4096 + lg * 8;

#define LOAD_K(TILE)                                                         \
    {                                                                        \
        const f16* _s = Kb + ((size_t)((TILE) * 32 + w * 4)) * 512 + lane * 8; \
        _Pragma("unroll")                                                    \
        for (int i = 0; i < 4; ++i)                                          \
            kreg[i] = *reinterpret_cast<const f16x8*>(_s + (size_t)i * 512); \
    }
#define WRITE_K(BUF)                                                         \
    {                                                                        \
        _Pragma("unroll")                                                    \
        for (int i = 0; i < 4; ++i)                                          \
            *reinterpret_cast<f16x8*>(&Km[BUF][w * 4 + i][lane * 8]) = kreg[i]; \
    }
#define LOAD_V(DST, TILE)                                                    \
    {                                                                        \
        const f16* _s = Vbase + (TILE) * 32;                                 \
        _Pragma("unroll")                                                    \
        for (int fc = 0; fc < 4; ++fc)                                       \
            DST[fc] = *reinterpret_cast<const f16x8*>(_s + (size_t)fc * 16 * 4096); \
    }

    // prologue
    LOAD_K(0);
    LOAD_V(vfr, 0);
    WRITE_K(0);
    LOAD_K(1);
    __syncthreads();            // Km[0] visible, stats initialized

    int cur = 0;
    for (int tile = 0; tile < 128; ++tile) {
        // issue V(t+1) loads (consumed next iteration's PV)
        if (tile < 127) LOAD_V(vnx, tile + 1);

        // QK: wave's 16x16 S-tile, two independent 8-deep MFMA chains
        f32x4 sA = {0.f, 0.f, 0.f, 0.f}, sB = {0.f, 0.f, 0.f, 0.f};
        int mr = mh * 16 + li;
#pragma unroll
        for (int kk = 0; kk < 16; kk += 2) {
            f16x8 b0 = *reinterpret_cast<const f16x8*>(&Km[cur][mr][kk * 32 + lg * 8]);
            f16x8 b1 = *reinterpret_cast<const f16x8*>(&Km[cur][mr][(kk + 1) * 32 + lg * 8]);
            sA = MFMA16(qf[kk], b0, sA);
            sB = MFMA16(qf[kk + 1], b1, sB);
        }
        int sr = aq * 16 + lg * 4;
        int sc = mh * 16 + li;
#pragma unroll
        for (int e = 0; e < 4; ++e) Sl[sr + e][sc] = sA[e] + sB[e];
        __syncthreads();   // bar B: S complete, Km[cur] reads done

        // softmax: wave w handles rows w*8 .. w*8+8
        {
            int m = lane & 31;
            int half = lane >> 5;
#pragma unroll
            for (int p = 0; p < 4; ++p) {
                int r = w * 8 + p * 2 + half;
                float x = Sl[r][m];
                float mx = x;
#pragma unroll
                for (int off = 1; off < 32; off <<= 1)
                    mx = fmaxf(mx, __shfl_xor(mx, off));
                float Mold = Mrow[r];
                bool needR = (mx - Mold) > 4.0f;        // defer-max THR=4
                float Mnew = needR ? mx : Mold;
                float pr = __expf(x - Mnew);
                float rsum = pr;
#pragma unroll
                for (int off = 1; off < 32; off <<= 1)
                    rsum += __shfl_xor(rsum, off);
                Pl[r][m] = (f16)pr;
                if (m == 0) {
                    float rr = needR ? __expf(Mold - Mnew) : 1.f;
                    Mrow[r] = Mnew;
                    Lrow[r] = Lrow[r] * rr + rsum;
                    Rrow[r] = rr;
                    if (needR) Rflag[tile & 1] = 1;
                }
            }
            if (t == 0) Rflag[(tile + 1) & 1] = 0;
        }

        // K(t+1): reg -> LDS (other buffer); then issue K(t+2) loads
        if (tile < 127) WRITE_K(cur ^ 1);
        if (tile < 126) LOAD_K(tile + 2);

        __syncthreads();   // bar C: P ready AND Km[cur^1] ready

        // PV: rescale only when some row updated its max
        if (Rflag[tile & 1]) {
#pragma unroll
            for (int fn = 0; fn < 4; ++fn) {
                f32x4 rv = *reinterpret_cast<const f32x4*>(&Rrow[fn * 16 + lg * 4]);
#pragma unroll
                for (int fc = 0; fc < 4; ++fc)
#pragma unroll
                    for (int e = 0; e < 4; ++e) acc[fn][fc][e] *= rv[e];
            }
        }
        f16x8 af[4];
#pragma unroll
        for (int fn = 0; fn < 4; ++fn)
            af[fn] = *reinterpret_cast<const f16x8*>(&Pl[fn * 16 + li][lg * 8]);
#pragma unroll
        for (int fn = 0; fn < 4; ++fn)
#pragma unroll
            for (int fc = 0; fc < 4; ++fc)
                acc[fn][fc] = MFMA16(af[fn], vfr[fc], acc[fn][fc]);

        if (tile < 127) {
#pragma unroll
            for (int fc = 0; fc < 4; ++fc) vfr[fc] = vnx[fc];
        }
        cur ^= 1;
    }

    // epilogue: divide by L, store out[b][c][n]
    float* ob = out + (size_t)b * 512 * 4096;
#pragma unroll
    for (int fn = 0; fn < 4; ++fn) {
        f32x4 lv = *reinterpret_cast<const f32x4*>(&Lrow[fn * 16 + lg * 4]);
        float linv[4];
#pragma unroll
        for (int e = 0; e < 4; ++e) linv[e] = 1.f / lv[e];
#pragma unroll
        for (int fc = 0; fc < 4; ++fc) {
            int c = w * 64 + fc * 16 + li;
#pragma unroll
            for (int e = 0; e < 4; ++e) {
                int n = n0 + fn * 16 + lg * 4 + e;
                ob[(size_t)c * 4096 + n] = acc[fn][fc][e] * linv[e];
            }
        }
    }
#undef LOAD_K
#undef WRITE_K
#undef LOAD_V
}

// ---------------------------------------------------------------------------
extern "C" void kernel_launch(void* const* d_in, const int* in_sizes, int n_in,
                              void* d_out, int out_size, void* d_ws, size_t ws_size,
                              hipStream_t stream)
{
    const float* content = (const float*)d_in[0];
    const float* style   = (const float*)d_in[1];
    const float* Wq = (const float*)d_in[2];
    const float* bq = (const float*)d_in[3];
    const float* Wk = (const float*)d_in[4];
    const float* bk = (const float*)d_in[5];
    const float* Wv = (const float*)d_in[6];
    const float* bv = (const float*)d_in[7];
    float* out = (float*)d_out;

    const size_t TEN = (size_t)4 * 4096 * 512;
    f16* Qt = (f16*)d_ws;
    f16* Kt = Qt + TEN;
    f16* Vc = Kt + TEN;
    float* mu = (float*)(Vc + TEN);
    float* rs = mu + 4096;

    hipLaunchKernelGGL(stats_kernel, dim3(4096), dim3(256), 0, stream,
                       content, style, mu, rs);
    hipLaunchKernelGGL(qkv_kernel, dim3(32, 4, 12), dim3(256), 0, stream,
                       content, style, Wq, bq, Wk, bk, Wv, bv, mu, rs, Qt, Kt, Vc);
    hipLaunchKernelGGL(attn_kernel, dim3(64, 4), dim3(512), 0, stream,
                       Qt, Kt, Vc, out);
}

// Round 4
// 341.969 us; speedup vs baseline: 2.7639x; 1.5328x over previous
//
#include <hip/hip_runtime.h>

typedef _Float16 f16;
typedef _Float16 f16x4 __attribute__((ext_vector_type(4)));
typedef _Float16 f16x8 __attribute__((ext_vector_type(8)));
typedef float f32x4 __attribute__((ext_vector_type(4)));

#define MFMA16(a, b, c) __builtin_amdgcn_mfma_f32_16x16x32_f16(a, b, c, 0, 0, 0)

// ---------------- Kernel 1: per-(tensor,b,c) mean / inv-std ----------------
__global__ __launch_bounds__(256) void stats_kernel(
    const float* __restrict__ content, const float* __restrict__ style,
    float* __restrict__ mu, float* __restrict__ rs)
{
    int bid = blockIdx.x;            // tensor*2048 + b*512 + c
    int tensor = bid >> 11;
    int row = bid & 2047;
    const float* src = (tensor ? style : content) + (size_t)row * 4096;
    int t = threadIdx.x;
    float s = 0.f, ss = 0.f;
    for (int i = t; i < 1024; i += 256) {
        float4 v = reinterpret_cast<const float4*>(src)[i];
        s  += v.x + v.y + v.z + v.w;
        ss += v.x * v.x + v.y * v.y + v.z * v.z + v.w * v.w;
    }
    for (int off = 32; off > 0; off >>= 1) {
        s  += __shfl_down(s, off);
        ss += __shfl_down(ss, off);
    }
    __shared__ float sb[4], ssb[4];
    int wv = t >> 6;
    if ((t & 63) == 0) { sb[wv] = s; ssb[wv] = ss; }
    __syncthreads();
    if (t == 0) {
        float S  = sb[0] + sb[1] + sb[2] + sb[3];
        float SS = ssb[0] + ssb[1] + ssb[2] + ssb[3];
        float m  = S * (1.f / 4096.f);
        float var = (SS - 4096.f * m * m) * (1.f / 4095.f);
        mu[bid] = m;
        rs[bid] = rsqrtf(var + 1e-5f);
    }
}

// ---------------- Kernel 2: fused norm + 1x1-conv (Q,K,V) -----------------
__global__ __launch_bounds__(256) void qkv_kernel(
    const float* __restrict__ content, const float* __restrict__ style,
    const float* __restrict__ Wq, const float* __restrict__ bq,
    const float* __restrict__ Wk, const float* __restrict__ bk,
    const float* __restrict__ Wv, const float* __restrict__ bv,
    const float* __restrict__ mu, const float* __restrict__ rs,
    f16* __restrict__ Qt, f16* __restrict__ Kt, f16* __restrict__ Vc)
{
    int z = blockIdx.z;
    int b = z / 3, p = z % 3;
    int n0 = blockIdx.x * 128;
    int o0 = blockIdx.y * 128;
    const float* X    = (p == 0 ? content : style) + (size_t)b * 512 * 4096;
    const float* W    = (p == 0 ? Wq : (p == 1 ? Wk : Wv));
    const float* bias = (p == 0 ? bq : (p == 1 ? bk : bv));
    const float* muT = mu + (p == 0 ? 0 : 2048) + b * 512;
    const float* rsT = rs + (p == 0 ? 0 : 2048) + b * 512;
    bool norm = (p < 2);

    __shared__ __align__(16) f16 Xt[128][40];
    __shared__ __align__(16) f16 Wl[128][40];

    int t = threadIdx.x;
    int lane = t & 63, w = t >> 6;
    int wn = (w & 1) * 64, wo = (w >> 1) * 64;
    int lg = lane >> 4, li = lane & 15;

    f32x4 acc[4][4];
#pragma unroll
    for (int i = 0; i < 4; ++i)
#pragma unroll
        for (int j = 0; j < 4; ++j)
#pragma unroll
            for (int e = 0; e < 4; ++e) acc[i][j][e] = 0.f;

    for (int kk = 0; kk < 16; ++kk) {
        int c0 = kk * 32;
        __syncthreads();
#pragma unroll
        for (int r = 0; r < 4; ++r) {
            int linear = r * 256 + t;
            int c  = linear >> 5;
            int nq = linear & 31;
            float4 v = reinterpret_cast<const float4*>(X + (size_t)(c0 + c) * 4096 + n0)[nq];
            float m = 0.f, sc = 1.f;
            if (norm) { m = muT[c0 + c]; sc = rsT[c0 + c]; }
            int n = nq * 4;
            Xt[n + 0][c] = (f16)((v.x - m) * sc);
            Xt[n + 1][c] = (f16)((v.y - m) * sc);
            Xt[n + 2][c] = (f16)((v.z - m) * sc);
            Xt[n + 3][c] = (f16)((v.w - m) * sc);
        }
#pragma unroll
        for (int r = 0; r < 4; ++r) {
            int linear = r * 256 + t;
            int o  = linear >> 3;
            int cq = linear & 7;
            float4 v = reinterpret_cast<const float4*>(W + (size_t)(o0 + o) * 512 + c0)[cq];
            int c = cq * 4;
            Wl[o][c + 0] = (f16)v.x;
            Wl[o][c + 1] = (f16)v.y;
            Wl[o][c + 2] = (f16)v.z;
            Wl[o][c + 3] = (f16)v.w;
        }
        __syncthreads();

        f16x8 xf[4], wf[4];
#pragma unroll
        for (int f = 0; f < 4; ++f) {
            xf[f] = *reinterpret_cast<const f16x8*>(&Xt[wn + f * 16 + li][lg * 8]);
            wf[f] = *reinterpret_cast<const f16x8*>(&Wl[wo + f * 16 + li][lg * 8]);
        }
        if (p < 2) {
#pragma unroll
            for (int i = 0; i < 4; ++i)
#pragma unroll
                for (int j = 0; j < 4; ++j)
                    acc[i][j] = MFMA16(xf[i], wf[j], acc[i][j]);
        } else {
#pragma unroll
            for (int i = 0; i < 4; ++i)
#pragma unroll
                for (int j = 0; j < 4; ++j)
                    acc[i][j] = MFMA16(wf[i], xf[j], acc[i][j]);
        }
    }

    if (p < 2) {
        f16* dst = (p == 0 ? Qt : Kt) + (size_t)b * 4096 * 512;
#pragma unroll
        for (int j = 0; j < 4; ++j) {
            int o = o0 + wo + j * 16 + li;
            float bb = bias[o];
#pragma unroll
            for (int i = 0; i < 4; ++i)
#pragma unroll
                for (int e = 0; e < 4; ++e) {
                    int n = n0 + wn + i * 16 + lg * 4 + e;
                    dst[(size_t)n * 512 + o] = (f16)(acc[i][j][e] + bb);
                }
        }
    } else {
#pragma unroll
        for (int i = 0; i < 4; ++i)
#pragma unroll
            for (int e = 0; e < 4; ++e) {
                int o = o0 + wo + i * 16 + lg * 4 + e;
                float bb = bias[o];
#pragma unroll
                for (int j = 0; j < 4; ++j) {
                    int n = n0 + wn + j * 16 + li;
                    Vc[((size_t)b * 512 + o) * 4096 + n] = (f16)(acc[i][j][e] + bb);
                }
            }
    }
}

// ---------------- Kernel 3: flash attention, producer/consumer -------------
// 512 thr = 4 QK waves (w0-3) + 4 PV waves (w4-7); TQ=64, KVBLK=64.
// QK wave nr: q-rows nr*16+li; swapped MFMA S^T=mfma(K,Q) -> softmax wave-local.
// PV wave pw: c-slice pw*128, consumes P(t-1) from LDS, V from own registers.
// ONE barrier per iteration; Km/Pl/Rrow ping-pong.
__global__ __launch_bounds__(512, 2) void attn_kernel(
    const f16* __restrict__ Qt, const f16* __restrict__ Kt,
    const f16* __restrict__ Vc, float* __restrict__ out)
{
    int bid = blockIdx.x;
    int orig = (bid & 7) * 32 + (bid >> 3);   // XCD chunking: XCD i -> one b, contiguous n0
    int b = orig >> 6;
    int n0 = (orig & 63) * 64;

    int t = threadIdx.x;
    int lane = t & 63, w = t >> 6;
    int lg = lane >> 4, li = lane & 15;

    __shared__ __align__(16) f16 Km[2][64][520];   // K ping-pong [m][c]
    __shared__ __align__(16) f16 Pl[2][64][72];    // P ping-pong [n][m]
    __shared__ float Rrow[2][64];
    __shared__ float Lrow[64];
    __shared__ int   Rflag[2][4];

    const f16* Qb = Qt + (size_t)b * 4096 * 512;
    const f16* Kb = Kt + (size_t)b * 4096 * 512;
    const f16* Vb = Vc + (size_t)b * 512 * 4096;

    if (w < 4) {
        // =============== QK / softmax wave ===============
        int nr = w;
        f16x8 qf[16];
#pragma unroll
        for (int kk = 0; kk < 16; ++kk)
            qf[kk] = *reinterpret_cast<const f16x8*>(
                Qb + (size_t)(n0 + nr * 16 + li) * 512 + kk * 32 + lg * 8);

        f16x8 kreg[16];
#define LOADK(TILE)                                                            \
        {                                                                      \
            const f16* _s = Kb + ((size_t)(TILE) * 64 + nr * 16) * 512 + lane * 8; \
            _Pragma("unroll")                                                  \
            for (int r = 0; r < 16; ++r)                                       \
                kreg[r] = *reinterpret_cast<const f16x8*>(_s + (size_t)r * 512); \
        }
#define WRITEK(BUF)                                                            \
        {                                                                      \
            _Pragma("unroll")                                                  \
            for (int r = 0; r < 16; ++r)                                       \
                *reinterpret_cast<f16x8*>(&Km[BUF][nr * 16 + r][lane * 8]) = kreg[r]; \
        }
        LOADK(0);
        WRITEK(0);
        LOADK(1);
        float Mreg = -3.4e38f, Lreg = 0.f;
        __syncthreads();   // Km[0] complete (cross-QK-wave), pairs with PV prologue barrier

        for (int it = 0; it <= 64; ++it) {
            if (it <= 63) {
                int cur = it & 1;
                // --- S^T = K * Q^T : 4 independent 16-deep chains ---
                f32x4 s[4];
#pragma unroll
                for (int mg = 0; mg < 4; ++mg)
#pragma unroll
                    for (int e = 0; e < 4; ++e) s[mg][e] = 0.f;
                __builtin_amdgcn_s_setprio(1);
#pragma unroll
                for (int kk = 0; kk < 16; ++kk) {
#pragma unroll
                    for (int mg = 0; mg < 4; ++mg) {
                        f16x8 kf = *reinterpret_cast<const f16x8*>(
                            &Km[cur][mg * 16 + li][kk * 32 + lg * 8]);
                        s[mg] = MFMA16(kf, qf[kk], s[mg]);
                    }
                }
                __builtin_amdgcn_s_setprio(0);

                // --- wave-local online softmax (row n = nr*16+li) ---
                float mx = s[0][0];
#pragma unroll
                for (int mg = 0; mg < 4; ++mg)
#pragma unroll
                    for (int e = 0; e < 4; ++e) mx = fmaxf(mx, s[mg][e]);
                mx = fmaxf(mx, __shfl_xor(mx, 16));
                mx = fmaxf(mx, __shfl_xor(mx, 32));
                bool needR = (mx - Mreg) > 4.0f;          // defer-max THR=4
                float Mnew = needR ? mx : Mreg;
                float r = needR ? __expf(Mreg - Mnew) : 1.f;
                float sum = 0.f;
                float p[4][4];
#pragma unroll
                for (int mg = 0; mg < 4; ++mg)
#pragma unroll
                    for (int e = 0; e < 4; ++e) {
                        p[mg][e] = __expf(s[mg][e] - Mnew);
                        sum += p[mg][e];
                    }
                sum += __shfl_xor(sum, 16);
                sum += __shfl_xor(sum, 32);
                Lreg = Lreg * r + sum;
                Mreg = Mnew;
                // write P strip: Pl[cur][n][m], 4x f16x4 (8B) per lane
#pragma unroll
                for (int mg = 0; mg < 4; ++mg) {
                    f16x4 pk;
#pragma unroll
                    for (int e = 0; e < 4; ++e) pk[e] = (f16)p[mg][e];
                    *reinterpret_cast<f16x4*>(&Pl[cur][nr * 16 + li][mg * 16 + lg * 4]) = pk;
                }
                if (lg == 0) Rrow[cur][nr * 16 + li] = r;
                int any = __any(needR);
                if (lane == 0) Rflag[cur][nr] = any;

                // --- stage K(it+1), prefetch K(it+2) ---
                if (it <= 62) WRITEK(cur ^ 1);
                if (it <= 61) LOADK(it + 2);
            }
            if (it == 64 && lg == 0) Lrow[nr * 16 + li] = Lreg;
            __syncthreads();
        }
        // QK waves done (PV waves write the output)
#undef LOADK
#undef WRITEK
    } else {
        // =============== PV wave ===============
        int pw = w - 4;
        int c0 = pw * 128;
        f32x4 acc[4][8];
#pragma unroll
        for (int fn = 0; fn < 4; ++fn)
#pragma unroll
            for (int fc = 0; fc < 8; ++fc)
#pragma unroll
                for (int e = 0; e < 4; ++e) acc[fn][fc][e] = 0.f;
        f16x8 vfr[8][2];   // V frags [fc][ks] for tile (it-1)

        __syncthreads();   // pairs with QK prologue barrier

        for (int it = 0; it <= 64; ++it) {
            if (it >= 1) {
                int pp = (it - 1) & 1;
                int flag = Rflag[pp][0] | Rflag[pp][1] | Rflag[pp][2] | Rflag[pp][3];
                if (flag) {
#pragma unroll
                    for (int fn = 0; fn < 4; ++fn) {
                        f32x4 rv = *reinterpret_cast<const f32x4*>(&Rrow[pp][fn * 16 + lg * 4]);
#pragma unroll
                        for (int fc = 0; fc < 8; ++fc)
#pragma unroll
                            for (int e = 0; e < 4; ++e) acc[fn][fc][e] *= rv[e];
                    }
                }
                __builtin_amdgcn_s_setprio(1);
#pragma unroll
                for (int fn = 0; fn < 4; ++fn) {
                    f16x8 af0 = *reinterpret_cast<const f16x8*>(&Pl[pp][fn * 16 + li][lg * 8]);
                    f16x8 af1 = *reinterpret_cast<const f16x8*>(&Pl[pp][fn * 16 + li][32 + lg * 8]);
#pragma unroll
                    for (int fc = 0; fc < 8; ++fc) {
                        acc[fn][fc] = MFMA16(af0, vfr[fc][0], acc[fn][fc]);
                        acc[fn][fc] = MFMA16(af1, vfr[fc][1], acc[fn][fc]);
                    }
                }
                __builtin_amdgcn_s_setprio(0);
            }
            if (it <= 63) {
                // load V(it) frags for next iteration (drained at the barrier)
                const f16* vs = Vb + (size_t)(c0 + li) * 4096 + it * 64 + lg * 8;
#pragma unroll
                for (int fc = 0; fc < 8; ++fc) {
                    vfr[fc][0] = *reinterpret_cast<const f16x8*>(vs + (size_t)fc * 16 * 4096);
                    vfr[fc][1] = *reinterpret_cast<const f16x8*>(vs + (size_t)fc * 16 * 4096 + 32);
                }
            }
            __syncthreads();
        }

        // epilogue: divide by L, store out[b][c][n]
        float* ob = out + (size_t)b * 512 * 4096;
#pragma unroll
        for (int fn = 0; fn < 4; ++fn) {
            f32x4 lv = *reinterpret_cast<const f32x4*>(&Lrow[fn * 16 + lg * 4]);
            f32x4 linv;
#pragma unroll
            for (int e = 0; e < 4; ++e) linv[e] = 1.f / lv[e];
#pragma unroll
            for (int fc = 0; fc < 8; ++fc) {
                int c = c0 + fc * 16 + li;
                f32x4 o4;
#pragma unroll
                for (int e = 0; e < 4; ++e) o4[e] = acc[fn][fc][e] * linv[e];
                *reinterpret_cast<f32x4*>(ob + (size_t)c * 4096 + n0 + fn * 16 + lg * 4) = o4;
            }
        }
    }
}

// ---------------------------------------------------------------------------
extern "C" void kernel_launch(void* const* d_in, const int* in_sizes, int n_in,
                              void* d_out, int out_size, void* d_ws, size_t ws_size,
                              hipStream_t stream)
{
    const float* content = (const float*)d_in[0];
    const float* style   = (const float*)d_in[1];
    const float* Wq = (const float*)d_in[2];
    const float* bq = (const float*)d_in[3];
    const float* Wk = (const float*)d_in[4];
    const float* bk = (const float*)d_in[5];
    const float* Wv = (const float*)d_in[6];
    const float* bv = (const float*)d_in[7];
    float* out = (float*)d_out;

    const size_t TEN = (size_t)4 * 4096 * 512;
    f16* Qt = (f16*)d_ws;
    f16* Kt = Qt + TEN;
    f16* Vc = Kt + TEN;
    float* mu = (float*)(Vc + TEN);
    float* rs = mu + 4096;

    hipLaunchKernelGGL(stats_kernel, dim3(4096), dim3(256), 0, stream,
                       content, style, mu, rs);
    hipLaunchKernelGGL(qkv_kernel, dim3(32, 4, 12), dim3(256), 0, stream,
                       content, style, Wq, bq, Wk, bk, Wv, bv, mu, rs, Qt, Kt, Vc);
    hipLaunchKernelGGL(attn_kernel, dim3(256), dim3(512), 0, stream,
                       Qt, Kt, Vc, out);
}